// Round 3
// baseline (138.857 us; speedup 1.0000x reference)
//
#include <hip/hip_runtime.h>
#include <hip/hip_bf16.h>
#include <math.h>

#define B_N 8192
#define D_K 256
#define TILE 128
#define NT 1024             // 16 waves, 4x4 wave grid, 32x32 per wave -> acc = 16 regs/thread
#define NBLK 64             // B_N / TILE
#define NPAIR 2080          // NBLK*(NBLK+1)/2 upper-triangular tile pairs
#define NCLS 100
#define KEXP 28.8539008177792681f   // 20*log2(e): e^(sim-20) = 2^((dot-1)*KEXP)
#define KCH 64              // K elements per staged chunk (0-conflict 8-slot XOR swizzle)
#define NCHUNK 4            // D_K / KCH
#define GRID_MAIN 512       // persistent: 2 blocks/CU exactly; tiles claimed by work-stealing

typedef __attribute__((ext_vector_type(8))) short short8;
typedef __attribute__((ext_vector_type(4))) float f32x4;

template <bool V> struct BoolC { static constexpr bool value = V; };

__device__ __forceinline__ unsigned short f2bf(float x) {
    unsigned int u = __float_as_uint(x);
    unsigned int r = (u + 0x7FFFu + ((u >> 16) & 1u)) >> 16;
    return (unsigned short)r;
}

// async global->LDS, 16B per lane: dest = (wave-uniform) lds base + lane*16
__device__ __forceinline__ void gload_lds16(const short* g, short* l) {
    __builtin_amdgcn_global_load_lds(
        (const __attribute__((address_space(1))) void*)g,
        (__attribute__((address_space(3))) void*)l, 16, 0, 0);
}

// sum over each aligned 16-lane group on the VALU pipe (DPP butterfly+mirrors).
__device__ __forceinline__ float row_sum16(float v) {
    v += __int_as_float(__builtin_amdgcn_update_dpp(0, __float_as_int(v), 0xB1, 0xF, 0xF, true));
    v += __int_as_float(__builtin_amdgcn_update_dpp(0, __float_as_int(v), 0x4E, 0xF, 0xF, true));
    v += __int_as_float(__builtin_amdgcn_update_dpp(0, __float_as_int(v), 0x141, 0xF, 0xF, true));
    v += __int_as_float(__builtin_amdgcn_update_dpp(0, __float_as_int(v), 0x140, 0xF, 0xF, true));
    return v;
}

// tile index -> (a,b) upper-triangular pair
__device__ __forceinline__ void decode_pair(int t, int& a, int& b) {
    int bb = (int)((sqrtf(8.0f * t + 1.0f) - 1.0f) * 0.5f);
    while ((bb + 1) * (bb + 2) / 2 <= t) ++bb;
    while (bb * (bb + 1) / 2 > t) --bb;
    a = t - bb * (bb + 1) / 2;
    b = bb;
}

// -------- Kernel 1: normalize rows -> bf16; block 0 also: label hist + zero accums --------
__global__ __launch_bounds__(1024) void prep_kernel(
        const float* __restrict__ feat, unsigned short* __restrict__ fnorm,
        const int* __restrict__ labels, int* __restrict__ cnt,
        float* __restrict__ gscal, double* __restrict__ accum,
        unsigned int* __restrict__ done, unsigned int* __restrict__ wctr) {
    if (blockIdx.x == 0) {
        __shared__ int h[NCLS];
        int t = threadIdx.x;
        if (t < NCLS) h[t] = 0;
        if (t == 0) {
            gscal[0] = 0.f; gscal[1] = 0.f;
            accum[0] = 0.0; accum[1] = 0.0; accum[2] = 0.0;
            *done = 0u;
            *wctr = GRID_MAIN;      // tiles 0..GRID_MAIN-1 are implicit (block b starts on b)
        }
        __syncthreads();
        for (int r = t; r < B_N; r += 1024) atomicAdd(&h[labels[r]], 1);
        __syncthreads();
        if (t < NCLS) cnt[t] = h[t];
    }
    int wave = threadIdx.x >> 6, lane = threadIdx.x & 63;
    int row = blockIdx.x * 16 + wave;
    float4 v = *(const float4*)(feat + (size_t)row * D_K + lane * 4);
    float ss = v.x * v.x + v.y * v.y + v.z * v.z + v.w * v.w;
    #pragma unroll
    for (int off = 1; off < 64; off <<= 1) ss += __shfl_xor(ss, off);
    float inv = 1.0f / fmaxf(sqrtf(ss), 1e-12f);
    ushort4 o;
    o.x = f2bf(v.x * inv); o.y = f2bf(v.y * inv);
    o.z = f2bf(v.z * inv); o.w = f2bf(v.w * inv);
    *(ushort4*)(fnorm + (size_t)row * D_K + lane * 4) = o;
}

// -------- Kernel 2: persistent upper-triangular sim tiles --------
// Grid = 512 (2 blocks/CU exactly). Each block work-steals tiles via atomicAdd(wctr):
// kills the 2080-mod-512 straggler tail (~19% of round-2's 50us) and amortizes the per-tile
// prologue. Chunk c of a tile reads buffer (c+1)&1 (1,0,1,0), so buffer 1 is free at the
// post-K-loop barrier: the NEXT tile's chunk 0 is DMA'd there right after that barrier and
// the whole epilogue (~1-2k cyc) covers its latency. The next iteration's first barrier
// then drains an already-landed load (compiler emits vmcnt(0) at every barrier, so issuing
// any earlier would stall at the next barrier instead).
// NT=1024: acc[2][2] f32x4 = 16 regs -> fits 64-reg budget of (1024,8), no spill (round-2).
// K staging: 8-slot XOR swizzle, measured 0 bank conflicts.
__global__ __launch_bounds__(NT, 8) void main_kernel(
        const unsigned short* __restrict__ fnorm, const int* __restrict__ labels,
        float2* __restrict__ G, float* __restrict__ gscal, unsigned int* __restrict__ wctr) {
    __shared__ short As[2][TILE * KCH];   // 2 x 16 KB; As[0] reused as Rbuf in epilogue
    __shared__ short Bs[2][TILE * KCH];   // 2 x 16 KB; Bs[0] reused as Cbuf
    __shared__ int Ls[2 * TILE];
    __shared__ int ghs[16];
    __shared__ float gps[16];
    __shared__ int nxs;                   // stolen next-tile index (written kc=0, read post-K)

    const int tid = threadIdx.x;
    const int lane = tid & 63, wave = tid >> 6;
    const int wm = wave >> 2, wn = wave & 3;    // 4 (row) x 4 (col) waves; each 32x32
    const int l15 = lane & 15, lhi = lane >> 4;
    const short* fn = (const short*)fnorm;

    // staging coordinates (tile-invariant): thread stages 16B at row rs, slot tid&7
    // holding global sub-chunk cs (XOR swizzle keeps DMA linear, frag reads conflict-free)
    const int rs = tid >> 3, cs = (tid & 7) ^ (rs & 7);
    const int uds = (tid & ~63) * 8;            // shorts; wave-uniform base, HW adds lane*16B
    const int stg = rs * D_K + cs * 8;          // add row0/col0*D_K + chunk offset per use

    // fragment LDS offsets (tile- and chunk-invariant): sub-chunk k at slot k^(l15&7)
    const int ch8_0 = (lhi ^ (l15 & 7)) * 8;
    const int ch8_1 = ((4 + lhi) ^ (l15 & 7)) * 8;
    int aof[2][2], bof[2][2];   // [ks][frag]
    #pragma unroll
    for (int mi = 0; mi < 2; mi++) {
        aof[0][mi] = (wm * 32 + mi * 16 + l15) * KCH + ch8_0;
        aof[1][mi] = (wm * 32 + mi * 16 + l15) * KCH + ch8_1;
        bof[0][mi] = (wn * 32 + mi * 16 + l15) * KCH + ch8_0;
        bof[1][mi] = (wn * 32 + mi * 16 + l15) * KCH + ch8_1;
    }

    int tile = blockIdx.x, a, b;
    decode_pair(tile, a, b);
    int row0 = a * TILE, col0 = b * TILE;
    bool diag = (a == b);

    if (tid < 128) Ls[tid] = labels[row0 + tid];
    else if (tid < 256) Ls[tid] = labels[col0 + tid - 128];

    // prologue: chunk 0 of first tile -> buffer 1
    gload_lds16(fn + row0 * D_K + stg, &As[1][uds]);
    if (!diag) gload_lds16(fn + col0 * D_K + stg, &Bs[1][uds]);

    for (;;) {
        const int arow = row0 * D_K + stg;
        const int brow = col0 * D_K + stg;

        f32x4 acc[2][2];
        #pragma unroll
        for (int i = 0; i < 2; i++)
            #pragma unroll
            for (int j = 0; j < 2; j++) acc[i][j] = {0.f, 0.f, 0.f, 0.f};

        #pragma unroll
        for (int kc = 0; kc < NCHUNK; ++kc) {
            const int buf = (kc + 1) & 1;       // 1,0,1,0
            __syncthreads();   // drains DMA of chunk kc into buf; protects buffer reuse
            if (kc == 0) {
                if (tid == 0) nxs = atomicAdd(wctr, 1u);
                if (lane == 0) ghs[wave] = 0;   // after barrier: prev tid-0 read is done
            }
            if (kc < NCHUNK - 1) {              // prefetch chunk kc+1 into the other buffer
                const int nb = buf ^ 1, ko = (kc + 1) * KCH;
                gload_lds16(fn + arow + ko, &As[nb][uds]);
                if (!diag) gload_lds16(fn + brow + ko, &Bs[nb][uds]);
            }
            const short* Asrc = As[buf];
            const short* Bsrc = diag ? As[buf] : Bs[buf];
            #pragma unroll
            for (int ks = 0; ks < 2; ++ks) {
                short8 af[2], bfr[2];
                #pragma unroll
                for (int mi = 0; mi < 2; mi++) af[mi] = *(const short8*)&Asrc[aof[ks][mi]];
                #pragma unroll
                for (int ni = 0; ni < 2; ni++) bfr[ni] = *(const short8*)&Bsrc[bof[ks][ni]];
                #pragma unroll
                for (int mi = 0; mi < 2; mi++)
                    #pragma unroll
                    for (int ni = 0; ni < 2; ni++)
                        acc[mi][ni] = __builtin_amdgcn_mfma_f32_16x16x32_bf16(af[mi], bfr[ni], acc[mi][ni], 0, 0, 0);
            }
        }
        __syncthreads();   // chunk-3 (buf 0) reads done: As[0]/Bs[0] free for Rbuf/Cbuf

        // ---- steal result + next-tile chunk-0 prefetch (epilogue covers its latency) ----
        const int nx = nxs;
        int na = 0, nb2 = 0, nrow0 = 0, ncol0 = 0;
        bool ndiag = false;
        if (nx < NPAIR) {
            decode_pair(nx, na, nb2);
            nrow0 = na * TILE; ncol0 = nb2 * TILE; ndiag = (na == nb2);
            gload_lds16(fn + nrow0 * D_K + stg, &As[1][uds]);      // buf1: free (last read kc=2)
            if (!ndiag) gload_lds16(fn + ncol0 * D_K + stg, &Bs[1][uds]);
        }

        // ---- Epilogue. C/D layout: col = lane&15, row = (lane>>4)*4 + reg ----
        float2* Rbuf = (float2*)As[0];   // [wn 0..3][128]
        float2* Cbuf = (float2*)Bs[0];   // [wm 0..3][128]

        int lc[2], colg[2];
        #pragma unroll
        for (int ni = 0; ni < 2; ni++) {
            int c = wn * 32 + ni * 16 + l15;
            lc[ni] = Ls[128 + c];
            colg[ni] = col0 + c;
        }

        auto body = [&](auto DIAGC) {
            constexpr bool DIAG = decltype(DIAGC)::value;
            float cD[2] = {0.f, 0.f};
            float gp = 0.f;           // sum of positive-pair dots (this tile)
            bool anyhi = false;       // lane-mask predicate (SALU)

            #pragma unroll
            for (int mi = 0; mi < 2; mi++) {
                #pragma unroll
                for (int reg = 0; reg < 4; reg++) {
                    int rloc = wm * 32 + mi * 16 + lhi * 4 + reg;
                    int rowg = row0 + rloc;
                    int lr = Ls[rloc];
                    float d = 0.f;
                    #pragma unroll
                    for (int ni = 0; ni < 2; ni++) {
                        float dot = acc[mi][ni][reg];
                        float e = __builtin_exp2f((dot - 1.0f) * KEXP);   // e^(sim-20)
                        bool ns = !DIAG || (rowg != colg[ni]);   // off-diag: folds to true
                        float ev = ns ? e : 0.f;
                        d += ev; cD[ni] += ev;
                        bool ps = ns && (lr == lc[ni]);
                        gp += ps ? dot : 0.f;
                        anyhi = anyhi | (ps & (dot > 0.7f));
                    }
                    d = row_sum16(d);                  // VALU pipe, not LDS pipe
                    if (l15 == 0) Rbuf[wn * 128 + rloc] = {d, 0.f};
                }
            }

            if (!DIAG) {
                #pragma unroll
                for (int ni = 0; ni < 2; ni++) {
                    cD[ni] += __shfl_xor(cD[ni], 16);
                    cD[ni] += __shfl_xor(cD[ni], 32);
                }
                if (lhi == 0) {
                    #pragma unroll
                    for (int ni = 0; ni < 2; ni++)
                        Cbuf[wm * 128 + wn * 32 + ni * 16 + l15] = {cD[ni], 0.f};
                }
            }

            gp = row_sum16(gp);
            gp += __shfl_xor(gp, 16);
            gp += __shfl_xor(gp, 32);
            if (lane == 0) gps[wave] = gp;

            // ---- Rare path: any high-similarity positive in this wave ----
            if (__any(anyhi)) {
                float cR[2] = {0.f, 0.f};
                int nhi = 0;
                #pragma unroll
                for (int mi = 0; mi < 2; mi++) {
                    #pragma unroll
                    for (int reg = 0; reg < 4; reg++) {
                        int rloc = wm * 32 + mi * 16 + lhi * 4 + reg;
                        int rowg = row0 + rloc;
                        int lr = Ls[rloc];
                        float rx = 0.f;
                        #pragma unroll
                        for (int ni = 0; ni < 2; ni++) {
                            float dot = acc[mi][ni][reg];
                            bool ns = !DIAG || (rowg != colg[ni]);
                            bool hi = ns && (lr == lc[ni]) && (dot > 0.7f);
                            float e = hi ? __builtin_exp2f((dot - 1.0f) * KEXP) : 0.f;
                            rx += e; cR[ni] += e; nhi += hi ? 1 : 0;
                        }
                        rx = row_sum16(rx);
                        if (l15 == 0) Rbuf[wn * 128 + rloc].y = rx;
                    }
                }
                if (!DIAG) {
                    #pragma unroll
                    for (int ni = 0; ni < 2; ni++) {
                        cR[ni] += __shfl_xor(cR[ni], 16);
                        cR[ni] += __shfl_xor(cR[ni], 32);
                    }
                    if (lhi == 0) {
                        #pragma unroll
                        for (int ni = 0; ni < 2; ni++)
                            Cbuf[wm * 128 + wn * 32 + ni * 16 + l15].y = cR[ni];
                    }
                }
                #pragma unroll
                for (int off = 1; off < 64; off <<= 1) nhi += __shfl_xor(nhi, off);
                if (lane == 0) ghs[wave] = nhi;
            }
        };
        if (diag) body(BoolC<true>{});
        else body(BoolC<false>{});
        __syncthreads();

        if (tid < 128) {
            int r = tid;
            float2 a0 = Rbuf[r], a1 = Rbuf[128 + r], a2 = Rbuf[256 + r], a3 = Rbuf[384 + r];
            G[(size_t)b * B_N + row0 + r] = {a0.x + a1.x + a2.x + a3.x, a0.y + a1.y + a2.y + a3.y};
        } else if (tid < 256 && !diag) {
            int c = tid - 128;
            float2 a0 = Cbuf[c], a1 = Cbuf[128 + c], a2 = Cbuf[256 + c], a3 = Cbuf[384 + c];
            G[(size_t)a * B_N + col0 + c] = {a0.x + a1.x + a2.x + a3.x, a0.y + a1.y + a2.y + a3.y};
        }
        if (tid == 0) {
            float w = diag ? 1.0f : 2.0f;   // off-diag tile stands for (i,j) and (j,i)
            float gpt = 0.f;
            int tot = 0;
            #pragma unroll
            for (int i = 0; i < 16; i++) { gpt += gps[i]; tot += ghs[i]; }
            atomicAdd(&gscal[0], w * gpt);
            if (tot > 0) atomicAdd(&gscal[1], w * (float)tot);
        }

        if (nx >= NPAIR) break;
        // next tile's labels: Ls reads of this tile all happened before the barrier above;
        // next reads are >=4 barriers away (K-loop), so no extra sync needed
        if (tid < 128) Ls[tid] = labels[nrow0 + tid];
        else if (tid < 256) Ls[tid] = labels[ncol0 + tid - 128];
        a = na; b = nb2; row0 = nrow0; col0 = ncol0; diag = ndiag;
    }
}

// -------- Kernel 3: per-row reduction over 64 slots + last-block final assembly --------
__global__ void finalize_kernel(const float2* __restrict__ G, const int* __restrict__ labels,
                                const int* __restrict__ cnt, const float* __restrict__ gscal,
                                double* __restrict__ accum, unsigned int* __restrict__ done,
                                float* __restrict__ out) {
    int lane = threadIdx.x & 63, q = threadIdx.x >> 6;   // q = slot quarter
    int r = blockIdx.x * 64 + lane;
    float d = 0.f, rx = 0.f;
    #pragma unroll
    for (int s = 0; s < 16; ++s) {
        float2 g = G[(size_t)(q * 16 + s) * B_N + r];
        d += g.x; rx += g.y;
    }
    __shared__ float2 sh[4][64];
    sh[q][lane] = {d, rx};
    __syncthreads();
    if (threadIdx.x < 64) {
        int rr = blockIdx.x * 64 + threadIdx.x;
        float2 t0 = sh[0][threadIdx.x], t1 = sh[1][threadIdx.x];
        float2 t2 = sh[2][threadIdx.x], t3 = sh[3][threadIdx.x];
        float dd = t0.x + t1.x + t2.x + t3.x;
        float rr2 = t0.y + t1.y + t2.y + t3.y;
        float np = (float)(cnt[labels[rr]] - 1);
        float ld = logf(dd + 1e-12f) + 20.0f;             // log_denom (shift 20)
        double s1 = (double)np * (double)ld;
        double s2 = (double)np;
        double s3 = (rr2 > 0.f) ? (double)logf(rr2 + 1.0f) : 0.0;  // baseline=0: sim_max=20
        #pragma unroll
        for (int off = 1; off < 64; off <<= 1) {
            s1 += __shfl_xor(s1, off);
            s2 += __shfl_xor(s2, off);
            s3 += __shfl_xor(s3, off);
        }
        if (threadIdx.x == 0) {
            atomicAdd(&accum[0], s1);
            atomicAdd(&accum[1], s2);
            atomicAdd(&accum[2], s3);
            __threadfence();
            unsigned int tk = atomicAdd(done, 1u);
            if (tk == gridDim.x - 1) {           // last block assembles the scalar
                double a1 = atomicAdd(&accum[0], 0.0);
                double a2 = atomicAdd(&accum[1], 0.0);
                double a3 = atomicAdd(&accum[2], 0.0);
                double gp = (double)gscal[0];    // sum over ordered pos pairs of dot
                double gh = (double)gscal[1];    // count of high ordered pairs
                double scl = (a2 > 0.0) ? (a1 - 20.0 * gp) / fmax(a2, 1.0) : 0.0;
                double rel = (gh > 0.0) ? a3 / fmax(gh, 1.0) : 0.0;
                double tot = scl + rel;          // BETA = 1.0
                tot = fmin(fmax(tot, 0.0), 10.0);
                out[0] = (float)tot;
            }
        }
    }
}

extern "C" void kernel_launch(void* const* d_in, const int* in_sizes, int n_in,
                              void* d_out, int out_size, void* d_ws, size_t ws_size,
                              hipStream_t stream) {
    const float* feat = (const float*)d_in[0];
    const int* labels = (const int*)d_in[1];
    float* out = (float*)d_out;
    char* ws = (char*)d_ws;

    unsigned short* fnorm = (unsigned short*)(ws);                          // 4 MB
    float2* G          = (float2*)(ws + (size_t)4 * 1024 * 1024);           // 4 MB: [64][8192]
    int*    cnt        = (int*)(ws + (size_t)8 * 1024 * 1024);              // 400 B
    float*  gscal      = (float*)(ws + (size_t)8 * 1024 * 1024 + 1024);     // 8 B
    double* accum      = (double*)(ws + (size_t)8 * 1024 * 1024 + 2048);    // 24 B
    unsigned int* done = (unsigned int*)(ws + (size_t)8 * 1024 * 1024 + 3072); // 4 B
    unsigned int* wctr = (unsigned int*)(ws + (size_t)8 * 1024 * 1024 + 3136); // 4 B

    prep_kernel<<<B_N / 16, 1024, 0, stream>>>(feat, fnorm, labels, cnt, gscal, accum, done, wctr);
    main_kernel<<<GRID_MAIN, NT, 0, stream>>>(fnorm, labels, G, gscal, wctr);
    finalize_kernel<<<B_N / 64, 256, 0, stream>>>(G, labels, cnt, gscal, accum, done, out);
    (void)in_sizes; (void)n_in; (void)out_size; (void)ws_size;
}

// Round 4
// 130.367 us; speedup vs baseline: 1.0651x; 1.0651x over previous
//
#include <hip/hip_runtime.h>
#include <hip/hip_bf16.h>
#include <math.h>

#define B_N 8192
#define D_K 256
#define TILE 128
#define NT 256              // 4 waves, 2x2 wave grid, 64x64 per wave
#define NBLK 64             // B_N / TILE
#define NPAIR 2080          // NBLK*(NBLK+1)/2 upper-triangular tile pairs
#define NCLS 100
#define KEXP 28.8539008177792681f   // 20*log2(e): e^(sim-20) = 2^((dot-1)*KEXP)
#define KCH 32              // K elements per staged chunk
#define NCHUNK 8            // D_K / KCH
#define APAD 2048           // shorts: +4KB per As buffer -> LDS ~45KB pins 3 blocks/CU

typedef __attribute__((ext_vector_type(8))) short short8;
typedef __attribute__((ext_vector_type(4))) float f32x4;

template <bool V> struct BoolC { static constexpr bool value = V; };

__device__ __forceinline__ unsigned short f2bf(float x) {
    unsigned int u = __float_as_uint(x);
    unsigned int r = (u + 0x7FFFu + ((u >> 16) & 1u)) >> 16;
    return (unsigned short)r;
}

// async global->LDS, 16B per lane: dest = (wave-uniform) lds base + lane*16
__device__ __forceinline__ void gload_lds16(const short* g, short* l) {
    __builtin_amdgcn_global_load_lds(
        (const __attribute__((address_space(1))) void*)g,
        (__attribute__((address_space(3))) void*)l, 16, 0, 0);
}

// sum over each aligned 16-lane group on the VALU pipe (DPP butterfly+mirrors).
__device__ __forceinline__ float row_sum16(float v) {
    v += __int_as_float(__builtin_amdgcn_update_dpp(0, __float_as_int(v), 0xB1, 0xF, 0xF, true));
    v += __int_as_float(__builtin_amdgcn_update_dpp(0, __float_as_int(v), 0x4E, 0xF, 0xF, true));
    v += __int_as_float(__builtin_amdgcn_update_dpp(0, __float_as_int(v), 0x141, 0xF, 0xF, true));
    v += __int_as_float(__builtin_amdgcn_update_dpp(0, __float_as_int(v), 0x140, 0xF, 0xF, true));
    return v;
}

// -------- Kernel 1: normalize rows -> bf16; block 0 also: label hist + zero accums --------
__global__ void prep_kernel(const float* __restrict__ feat, unsigned short* __restrict__ fnorm,
                            const int* __restrict__ labels, int* __restrict__ cnt,
                            float* __restrict__ gscal, double* __restrict__ accum,
                            unsigned int* __restrict__ done) {
    if (blockIdx.x == 0) {
        __shared__ int h[NCLS];
        int t = threadIdx.x;
        if (t < NCLS) h[t] = 0;
        if (t == 0) {
            gscal[0] = 0.f; gscal[1] = 0.f;
            accum[0] = 0.0; accum[1] = 0.0; accum[2] = 0.0;
            *done = 0u;
        }
        __syncthreads();
        for (int r = t; r < B_N; r += 256) atomicAdd(&h[labels[r]], 1);
        __syncthreads();
        if (t < NCLS) cnt[t] = h[t];
    }
    int wave = threadIdx.x >> 6, lane = threadIdx.x & 63;
    int row = blockIdx.x * 4 + wave;
    float4 v = *(const float4*)(feat + (size_t)row * D_K + lane * 4);
    float ss = v.x * v.x + v.y * v.y + v.z * v.z + v.w * v.w;
    #pragma unroll
    for (int off = 1; off < 64; off <<= 1) ss += __shfl_xor(ss, off);
    float inv = 1.0f / fmaxf(sqrtf(ss), 1e-12f);
    ushort4 o;
    o.x = f2bf(v.x * inv); o.y = f2bf(v.y * inv);
    o.z = f2bf(v.z * inv); o.w = f2bf(v.w * inv);
    *(ushort4*)(fnorm + (size_t)row * D_K + lane * 4) = o;
}

// -------- Kernel 2: upper-triangular sim tiles --------
// NT=256: 4 waves in a 2x2 grid, each owning a 64x64 output sub-tile. vs round-2's 4x4:
// LDS read traffic HALVES (A panel read 2x not 4x, B 2x not 4x -> 256KB/tile) and the
// MFMA:ds_read ratio doubles to 2:1. acc[4][4] f32x4 = 64 regs; bounds(256,3) gives a
// 170-reg budget -> ~60 regs of slack, no spill (round-1/3 lesson: watch WRITE_SIZE).
// LDS ~45KB (As deliberately padded) pins 3 blocks/CU = 3 independent streams (the one
// axis never varied: r0/r2 both had 2 streams and identical 50us). 768 concurrent blocks
// -> 2080/768 = 2.71 -> 3-round makespan at 90% quantization efficiency.
// KCH=32 dbuf: rows are 64B so bank span = 16*parity + 4*slot; the round-1 swizzle
// slot=c^(r&3) repeated spans within 8-lane phases (its 3.2M conflicts). Fixed swizzle
// slot = c ^ ((r>>1)&3): every 8-lane phase hits 8 distinct 4-bank spans -> conflict-free.
// Staging: thread t holds phys slot t&3 of row t>>2 (+64/shot); its global sub-chunk is
// (t&3)^((t>>3)&3) (thread-constant). Fragment read slot = lhi ^ ((l15>>1)&3).
__global__ __launch_bounds__(NT, 3) void main_kernel(
        const unsigned short* __restrict__ fnorm, const int* __restrict__ labels,
        float2* __restrict__ G, float* __restrict__ gscal) {
    int bid = blockIdx.x;
    int b = (int)((sqrtf(8.0f * bid + 1.0f) - 1.0f) * 0.5f);
    while ((b + 1) * (b + 2) / 2 <= bid) ++b;
    while (b * (b + 1) / 2 > bid) --b;
    int a = bid - b * (b + 1) / 2;
    const int row0 = a * TILE, col0 = b * TILE;
    const bool diag = (a == b);

    __shared__ short As[2][TILE * KCH + APAD];  // 2 x (8KB + 4KB pad): pad pins 3 blk/CU
    __shared__ short Bs[2][TILE * KCH];         // 2 x 8KB
    __shared__ int Ls[2 * TILE];
    __shared__ float2 Rbuf[2 * TILE];           // [wn 0..1][128] row partials
    __shared__ float2 Cbuf[2 * TILE];           // [wm 0..1][128] col partials
    __shared__ int ghs[4];
    __shared__ float gps[4];

    const int tid = threadIdx.x;
    const int lane = tid & 63, wave = tid >> 6;
    const int wm = wave >> 1, wn = wave & 1;    // 2 (row) x 2 (col) waves; each 64x64
    const int l15 = lane & 15, lhi = lane >> 4;
    const short* fn = (const short*)fnorm;

    // staging: thread t stages 16B for row (t>>2)+64*shot, phys slot t&3, global
    // sub-chunk (t&3)^((t>>3)&3). Element offset within a panel (shot 0, chunk 0):
    const int rbase = (tid >> 2) * D_K + (((tid & 3) ^ ((tid >> 3) & 3))) * 8;
    const int uds = (tid & ~63) * 8;            // shorts; wave-uniform base, HW adds lane*16B

    if (tid < 128) Ls[tid] = labels[row0 + tid];
    else Ls[tid] = labels[col0 + tid - 128];
    if (lane == 0) ghs[wave] = 0;

    const int abase = row0 * D_K + rbase;       // 32-bit offsets: fnorm is 4MB
    const int bbase = col0 * D_K + rbase;

    // prologue: stage chunk 0 into buffer 0 (2 shots per panel: rows 0-63, 64-127)
    gload_lds16(fn + abase, &As[0][uds]);
    gload_lds16(fn + abase + 64 * D_K, &As[0][2048 + uds]);
    if (!diag) {
        gload_lds16(fn + bbase, &Bs[0][uds]);
        gload_lds16(fn + bbase + 64 * D_K, &Bs[0][2048 + uds]);
    }

    f32x4 acc[4][4];
    #pragma unroll
    for (int i = 0; i < 4; i++)
        #pragma unroll
        for (int j = 0; j < 4; j++) acc[i][j] = {0.f, 0.f, 0.f, 0.f};

    // fragment LDS offsets (chunk-invariant): slot = lhi ^ ((row>>1)&3) = lhi ^ ((l15>>1)&3)
    const int ch8 = (lhi ^ ((l15 >> 1) & 3)) * 8;
    int aoff[4], boff[4];
    #pragma unroll
    for (int i = 0; i < 4; i++) {
        aoff[i] = (wm * 64 + i * 16 + l15) * KCH + ch8;
        boff[i] = (wn * 64 + i * 16 + l15) * KCH + ch8;
    }

    #pragma unroll
    for (int kc = 0; kc < NCHUNK; ++kc) {
        const int cur = kc & 1;
        __syncthreads();   // drains DMA of chunk kc into buf[cur]; protects buffer reuse
        if (kc < NCHUNK - 1) {              // prefetch chunk kc+1 into the other buffer
            const int nxt = cur ^ 1, ko = (kc + 1) * KCH;
            gload_lds16(fn + abase + ko, &As[nxt][uds]);
            gload_lds16(fn + abase + 64 * D_K + ko, &As[nxt][2048 + uds]);
            if (!diag) {
                gload_lds16(fn + bbase + ko, &Bs[nxt][uds]);
                gload_lds16(fn + bbase + 64 * D_K + ko, &Bs[nxt][2048 + uds]);
            }
        }
        const short* Asrc = As[cur];
        const short* Bsrc = diag ? As[cur] : Bs[cur];
        short8 af[4], bfr[4];
        #pragma unroll
        for (int mi = 0; mi < 4; mi++) af[mi] = *(const short8*)&Asrc[aoff[mi]];
        #pragma unroll
        for (int ni = 0; ni < 4; ni++) bfr[ni] = *(const short8*)&Bsrc[boff[ni]];
        #pragma unroll
        for (int mi = 0; mi < 4; mi++)
            #pragma unroll
            for (int ni = 0; ni < 4; ni++)
                acc[mi][ni] = __builtin_amdgcn_mfma_f32_16x16x32_bf16(af[mi], bfr[ni], acc[mi][ni], 0, 0, 0);
    }
    // no barrier needed before epilogue: Rbuf/Cbuf are separate LDS, acc is in registers

    // ---- Epilogue. C/D layout: col = lane&15, row = (lane>>4)*4 + reg ----
    int lc[4], colg[4];
    #pragma unroll
    for (int ni = 0; ni < 4; ni++) {
        int c = wn * 64 + ni * 16 + l15;
        lc[ni] = Ls[128 + c];
        colg[ni] = col0 + c;
    }

    auto body = [&](auto DIAGC) {
        constexpr bool DIAG = decltype(DIAGC)::value;
        float cD[4] = {0.f, 0.f, 0.f, 0.f};
        float gp = 0.f;           // sum of positive-pair dots (this tile)
        bool anyhi = false;       // lane-mask predicate (SALU)

        #pragma unroll
        for (int mi = 0; mi < 4; mi++) {
            #pragma unroll
            for (int reg = 0; reg < 4; reg++) {
                int rloc = wm * 64 + mi * 16 + lhi * 4 + reg;
                int rowg = row0 + rloc;
                int lr = Ls[rloc];
                float d = 0.f;
                #pragma unroll
                for (int ni = 0; ni < 4; ni++) {
                    float dot = acc[mi][ni][reg];
                    float e = __builtin_exp2f((dot - 1.0f) * KEXP);   // e^(sim-20)
                    bool ns = !DIAG || (rowg != colg[ni]);   // off-diag: folds to true
                    float ev = ns ? e : 0.f;
                    d += ev; cD[ni] += ev;
                    bool ps = ns && (lr == lc[ni]);
                    gp += ps ? dot : 0.f;
                    anyhi = anyhi | (ps & (dot > 0.7f));
                }
                d = row_sum16(d);                  // VALU pipe, not LDS pipe
                if (l15 == 0) Rbuf[wn * 128 + rloc] = {d, 0.f};
            }
        }

        if (!DIAG) {
            #pragma unroll
            for (int ni = 0; ni < 4; ni++) {
                cD[ni] += __shfl_xor(cD[ni], 16);
                cD[ni] += __shfl_xor(cD[ni], 32);
            }
            if (lhi == 0) {
                #pragma unroll
                for (int ni = 0; ni < 4; ni++)
                    Cbuf[wm * 128 + wn * 64 + ni * 16 + l15] = {cD[ni], 0.f};
            }
        }

        gp = row_sum16(gp);
        gp += __shfl_xor(gp, 16);
        gp += __shfl_xor(gp, 32);
        if (lane == 0) gps[wave] = gp;

        // ---- Rare path: any high-similarity positive in this wave ----
        if (__any(anyhi)) {
            float cR[4] = {0.f, 0.f, 0.f, 0.f};
            int nhi = 0;
            #pragma unroll
            for (int mi = 0; mi < 4; mi++) {
                #pragma unroll
                for (int reg = 0; reg < 4; reg++) {
                    int rloc = wm * 64 + mi * 16 + lhi * 4 + reg;
                    int rowg = row0 + rloc;
                    int lr = Ls[rloc];
                    float rx = 0.f;
                    #pragma unroll
                    for (int ni = 0; ni < 4; ni++) {
                        float dot = acc[mi][ni][reg];
                        bool ns = !DIAG || (rowg != colg[ni]);
                        bool hi = ns && (lr == lc[ni]) && (dot > 0.7f);
                        float e = hi ? __builtin_exp2f((dot - 1.0f) * KEXP) : 0.f;
                        rx += e; cR[ni] += e; nhi += hi ? 1 : 0;
                    }
                    rx = row_sum16(rx);
                    if (l15 == 0) Rbuf[wn * 128 + rloc].y = rx;
                }
            }
            if (!DIAG) {
                #pragma unroll
                for (int ni = 0; ni < 4; ni++) {
                    cR[ni] += __shfl_xor(cR[ni], 16);
                    cR[ni] += __shfl_xor(cR[ni], 32);
                }
                if (lhi == 0) {
                    #pragma unroll
                    for (int ni = 0; ni < 4; ni++)
                        Cbuf[wm * 128 + wn * 64 + ni * 16 + l15].y = cR[ni];
                }
            }
            #pragma unroll
            for (int off = 1; off < 64; off <<= 1) nhi += __shfl_xor(nhi, off);
            if (lane == 0) ghs[wave] = nhi;
        }
    };
    if (diag) body(BoolC<true>{});
    else body(BoolC<false>{});
    __syncthreads();   // all Rbuf/Cbuf/gps/ghs writes visible

    if (tid < 128) {
        int r = tid;
        float2 a0 = Rbuf[r], a1 = Rbuf[128 + r];
        G[(size_t)b * B_N + row0 + r] = {a0.x + a1.x, a0.y + a1.y};
    } else if (!diag) {
        int c = tid - 128;
        float2 a0 = Cbuf[c], a1 = Cbuf[128 + c];
        G[(size_t)a * B_N + col0 + c] = {a0.x + a1.x, a0.y + a1.y};
    }
    if (tid == 0) {
        float w = diag ? 1.0f : 2.0f;   // off-diag tile stands for (i,j) and (j,i)
        float gpt = gps[0] + gps[1] + gps[2] + gps[3];
        atomicAdd(&gscal[0], w * gpt);
        int tot = ghs[0] + ghs[1] + ghs[2] + ghs[3];
        if (tot > 0) atomicAdd(&gscal[1], w * (float)tot);
    }
}

// -------- Kernel 3: per-row reduction over 64 slots + last-block final assembly --------
__global__ void finalize_kernel(const float2* __restrict__ G, const int* __restrict__ labels,
                                const int* __restrict__ cnt, const float* __restrict__ gscal,
                                double* __restrict__ accum, unsigned int* __restrict__ done,
                                float* __restrict__ out) {
    int lane = threadIdx.x & 63, q = threadIdx.x >> 6;   // q = slot quarter
    int r = blockIdx.x * 64 + lane;
    float d = 0.f, rx = 0.f;
    #pragma unroll
    for (int s = 0; s < 16; ++s) {
        float2 g = G[(size_t)(q * 16 + s) * B_N + r];
        d += g.x; rx += g.y;
    }
    __shared__ float2 sh[4][64];
    sh[q][lane] = {d, rx};
    __syncthreads();
    if (threadIdx.x < 64) {
        int rr = blockIdx.x * 64 + threadIdx.x;
        float2 t0 = sh[0][threadIdx.x], t1 = sh[1][threadIdx.x];
        float2 t2 = sh[2][threadIdx.x], t3 = sh[3][threadIdx.x];
        float dd = t0.x + t1.x + t2.x + t3.x;
        float rr2 = t0.y + t1.y + t2.y + t3.y;
        float np = (float)(cnt[labels[rr]] - 1);
        float ld = logf(dd + 1e-12f) + 20.0f;             // log_denom (shift 20)
        double s1 = (double)np * (double)ld;
        double s2 = (double)np;
        double s3 = (rr2 > 0.f) ? (double)logf(rr2 + 1.0f) : 0.0;  // baseline=0: sim_max=20
        #pragma unroll
        for (int off = 1; off < 64; off <<= 1) {
            s1 += __shfl_xor(s1, off);
            s2 += __shfl_xor(s2, off);
            s3 += __shfl_xor(s3, off);
        }
        if (threadIdx.x == 0) {
            atomicAdd(&accum[0], s1);
            atomicAdd(&accum[1], s2);
            atomicAdd(&accum[2], s3);
            __threadfence();
            unsigned int tk = atomicAdd(done, 1u);
            if (tk == gridDim.x - 1) {           // last block assembles the scalar
                double a1 = atomicAdd(&accum[0], 0.0);
                double a2 = atomicAdd(&accum[1], 0.0);
                double a3 = atomicAdd(&accum[2], 0.0);
                double gp = (double)gscal[0];    // sum over ordered pos pairs of dot
                double gh = (double)gscal[1];    // count of high ordered pairs
                double scl = (a2 > 0.0) ? (a1 - 20.0 * gp) / fmax(a2, 1.0) : 0.0;
                double rel = (gh > 0.0) ? a3 / fmax(gh, 1.0) : 0.0;
                double tot = scl + rel;          // BETA = 1.0
                tot = fmin(fmax(tot, 0.0), 10.0);
                out[0] = (float)tot;
            }
        }
    }
}

extern "C" void kernel_launch(void* const* d_in, const int* in_sizes, int n_in,
                              void* d_out, int out_size, void* d_ws, size_t ws_size,
                              hipStream_t stream) {
    const float* feat = (const float*)d_in[0];
    const int* labels = (const int*)d_in[1];
    float* out = (float*)d_out;
    char* ws = (char*)d_ws;

    unsigned short* fnorm = (unsigned short*)(ws);                          // 4 MB
    float2* G          = (float2*)(ws + (size_t)4 * 1024 * 1024);           // 4 MB: [64][8192]
    int*    cnt        = (int*)(ws + (size_t)8 * 1024 * 1024);              // 400 B
    float*  gscal      = (float*)(ws + (size_t)8 * 1024 * 1024 + 1024);     // 8 B
    double* accum      = (double*)(ws + (size_t)8 * 1024 * 1024 + 2048);    // 24 B
    unsigned int* done = (unsigned int*)(ws + (size_t)8 * 1024 * 1024 + 3072); // 4 B

    prep_kernel<<<B_N / 4, 256, 0, stream>>>(feat, fnorm, labels, cnt, gscal, accum, done);
    main_kernel<<<NPAIR, NT, 0, stream>>>(fnorm, labels, G, gscal);
    finalize_kernel<<<B_N / 64, 256, 0, stream>>>(G, labels, cnt, gscal, accum, done, out);
    (void)in_sizes; (void)n_in; (void)out_size; (void)ws_size;
}